// Round 3
// baseline (1914.362 us; speedup 1.0000x reference)
//
#include <hip/hip_runtime.h>

#define DI static __device__ __forceinline__

DI unsigned short f2bf(float f) {
  unsigned int u = __float_as_uint(f);
  u = (u + 0x7fffu + ((u >> 16) & 1u)) >> 16;
  return (unsigned short)u;
}
DI float bf2f(unsigned short h) { return __uint_as_float(((unsigned int)h) << 16); }

// ---------------------------------------------------------------------------
// FPS: one block per batch, 256 threads, 16 points/thread held in registers.
// Exact reference arithmetic: d = ((dx*dx + dy*dy) + dz*dz), no FMA.
// Tie-break: first (smallest) index wins, matching jnp.argmax.
// PASSED bit-exact vs np ref (output 0) — do not change arithmetic.
// ---------------------------------------------------------------------------
__global__ __launch_bounds__(256) void fps_kernel(const float* __restrict__ xyz,
                                                  float* __restrict__ newxyz) {
  const int b = blockIdx.x;
  const int t = threadIdx.x;
  const int lane = t & 63, wid = t >> 6;
  const float* X = xyz + (size_t)b * 4096 * 3;
  float px[16], py[16], pz[16], dist[16];
#pragma unroll
  for (int j = 0; j < 16; ++j) {
    int i = t + (j << 8);
    px[j] = X[i * 3 + 0];
    py[j] = X[i * 3 + 1];
    pz[j] = X[i * 3 + 2];
    dist[j] = 3.402823466e38f;
  }
  __shared__ float rv[4];
  __shared__ int ri[4];
  __shared__ float scx, scy, scz;
  float cx = X[0], cy = X[1], cz = X[2];  // farthest = 0 initially
  float* out = newxyz + (size_t)b * 1024 * 3;
  for (int s = 0; s < 1024; ++s) {
    if (t == 0) { out[s * 3 + 0] = cx; out[s * 3 + 1] = cy; out[s * 3 + 2] = cz; }
    float bv = -1.0f;
    int bi = 0;
#pragma unroll
    for (int j = 0; j < 16; ++j) {
      float dx = __fsub_rn(px[j], cx);
      float dy = __fsub_rn(py[j], cy);
      float dz = __fsub_rn(pz[j], cz);
      float d = __fadd_rn(__fadd_rn(__fmul_rn(dx, dx), __fmul_rn(dy, dy)), __fmul_rn(dz, dz));
      float nd = fminf(dist[j], d);
      dist[j] = nd;
      bool better = (nd > bv);  // strict >: earlier (smaller) index kept on ties
      bv = better ? nd : bv;
      bi = better ? (t + (j << 8)) : bi;
    }
#pragma unroll
    for (int off = 32; off >= 1; off >>= 1) {
      float v2 = __shfl_down(bv, off);
      int i2 = __shfl_down(bi, off);
      if (v2 > bv || (v2 == bv && i2 < bi)) { bv = v2; bi = i2; }
    }
    if (lane == 0) { rv[wid] = bv; ri[wid] = bi; }
    __syncthreads();
    float fv = rv[0];
    int fi = ri[0];
#pragma unroll
    for (int w = 1; w < 4; ++w) {
      float v2 = rv[w];
      int i2 = ri[w];
      if (v2 > fv || (v2 == fv && i2 < fi)) { fv = v2; fi = i2; }
    }
    if (t == (fi & 255)) { int jj = fi >> 8; scx = px[jj]; scy = py[jj]; scz = pz[jj]; }
    __syncthreads();
    cx = scx; cy = scy; cz = scz;
  }
}

// ---------------------------------------------------------------------------
// P0[b][n][o] = sum_c W0[o][3+c] * points[b][c][n]   (pushes mm0 through gather)
// block = 64 n x 64 o, 256 threads, register 4x4 tiles. grid = 16*64 = 1024.
// ---------------------------------------------------------------------------
__global__ __launch_bounds__(256) void p0_kernel(const float* __restrict__ points,
                                                 const float* __restrict__ w0,
                                                 float* __restrict__ P0) {
  const int b = blockIdx.x >> 6;
  const int n0 = (blockIdx.x & 63) << 6;
  const int t = threadIdx.x;
  __shared__ float W[64][64];  // [c][o]
  for (int idx = t; idx < 4096; idx += 256) {
    int c = idx >> 6, o = idx & 63;
    W[c][o] = w0[o * 67 + 3 + c];
  }
  __syncthreads();
  const int i = t >> 4, j = t & 15;
  const float* Pb = points + (size_t)b * 64 * 4096 + n0 + 4 * i;
  float acc[4][4] = {};
  for (int c = 0; c < 64; ++c) {
    float4 xv = *(const float4*)(Pb + (size_t)c * 4096);
    float4 wv = *(const float4*)&W[c][4 * j];
    float xr[4] = {xv.x, xv.y, xv.z, xv.w};
    float wr[4] = {wv.x, wv.y, wv.z, wv.w};
#pragma unroll
    for (int rr = 0; rr < 4; ++rr)
#pragma unroll
      for (int oi = 0; oi < 4; ++oi) acc[rr][oi] = fmaf(xr[rr], wr[oi], acc[rr][oi]);
  }
#pragma unroll
  for (int rr = 0; rr < 4; ++rr) {
    float4 vv = make_float4(acc[rr][0], acc[rr][1], acc[rr][2], acc[rr][3]);
    *(float4*)(P0 + ((size_t)b * 4096 + n0 + 4 * i + rr) * 64 + 4 * j) = vv;
  }
}

// ---------------------------------------------------------------------------
// Ball query fused with layer-0 stats accumulation.
// sqr emulates XLA-CPU fp32 arithmetic of the reference:
//   dot  = fma chain over d (Eigen/LLVM dot emitter, acc from 0)
//   cs/xs = plain rn ((x^2+y^2)+z^2)  (separate mul+reduce HLOs, no fma)
//   sqr  = rn((cs+xs) - rn(2*dot))    (2*dot exact, power of 2)
// Round-1 (rn dot) and round-2 (fp64) both mismatched -> fma-dot hypothesis.
// One wave per group, 4 groups per block, grid = 4096.
// ---------------------------------------------------------------------------
__global__ __launch_bounds__(256) void ballquery_stats0_kernel(
    const float* __restrict__ xyz, const float* __restrict__ newxyz,
    const float* __restrict__ P0, const float* __restrict__ w0,
    int* __restrict__ gidx, float* __restrict__ partials0) {
  const int t = threadIdx.x;
  const int lane = t & 63, w = t >> 6;
  const int gid = blockIdx.x * 4 + w;  // 0..16383
  const int b = gid >> 10;
  __shared__ int sel[4][32];
  __shared__ float red[4][128];
  const float* Xb = xyz + (size_t)b * 4096 * 3;
  const float cx = newxyz[(size_t)gid * 3 + 0];
  const float cy = newxyz[(size_t)gid * 3 + 1];
  const float cz = newxyz[(size_t)gid * 3 + 2];
  const float cs = __fadd_rn(__fadd_rn(__fmul_rn(cx, cx), __fmul_rn(cy, cy)), __fmul_rn(cz, cz));
  int cnt = 0, first = 0;
  bool found = false;
  for (int base = 0; base < 4096; base += 64) {
    int i = base + lane;
    float x = Xb[i * 3 + 0], y = Xb[i * 3 + 1], z = Xb[i * 3 + 2];
    float xs = __fadd_rn(__fadd_rn(__fmul_rn(x, x), __fmul_rn(y, y)), __fmul_rn(z, z));
    float dot = fmaf(cz, z, fmaf(cy, y, __fmul_rn(cx, x)));  // fma chain, d=0,1,2
    float sqr = __fsub_rn(__fadd_rn(cs, xs), __fmul_rn(2.0f, dot));
    bool ok = sqr <= 0.04f;
    unsigned long long mask = __ballot(ok);
    if (!found && mask != 0ull) { first = base + __builtin_ctzll(mask); found = true; }
    int pre = __popcll(mask & ((1ull << lane) - 1ull));
    int pos = cnt + pre;
    if (ok && pos < 32) sel[w][pos] = i;
    cnt += (int)__popcll(mask);
    if (cnt >= 32) break;
  }
  if (cnt < 32) {
    int pad = found ? first : 0;
    for (int p = cnt + lane; p < 32; p += 64) sel[w][p] = pad;
  }
  __syncthreads();
  if (lane < 32) gidx[(size_t)gid * 32 + lane] = sel[w][lane];
  // ---- stats for act0 (pre-BN layer0 output): lane = channel c ----
  const int c = lane;
  float wx = w0[c * 67 + 0], wy = w0[c * 67 + 1], wz = w0[c * 67 + 2];
  float ssum = 0.f, ssq = 0.f;
  const float* P0b = P0 + (size_t)b * 4096 * 64;
  for (int k = 0; k < 32; ++k) {
    int g = sel[w][k];
    float gx = Xb[g * 3 + 0] - cx, gy = Xb[g * 3 + 1] - cy, gz = Xb[g * 3 + 2] - cz;
    float a0 = fmaf(wx, gx, fmaf(wy, gy, fmaf(wz, gz, P0b[(size_t)g * 64 + c])));
    ssum += a0;
    ssq = fmaf(a0, a0, ssq);
  }
  red[w][c] = ssum;
  red[w][c + 64] = ssq;
  __syncthreads();
  if (t < 128) {
    float acc = red[0][t] + red[1][t] + red[2][t] + red[3][t];
    partials0[(size_t)t * 4096 + blockIdx.x] = acc;
  }
}

// ---------------------------------------------------------------------------
// finalize BN stats: scale = g*rsqrt(var+eps), shift = b - mean*scale
// ---------------------------------------------------------------------------
__global__ __launch_bounds__(256) void finalize_kernel(
    const float* __restrict__ partials, int C, int nblk,
    const float* __restrict__ gamma, const float* __restrict__ beta,
    float* __restrict__ scale, float* __restrict__ shift) {
  const int c = blockIdx.x, t = threadIdx.x;
  double s1 = 0.0, s2 = 0.0;
  for (int k = t; k < nblk; k += 256) {
    s1 += (double)partials[(size_t)c * nblk + k];
    s2 += (double)partials[(size_t)(C + c) * nblk + k];
  }
  __shared__ double r1[256], r2[256];
  r1[t] = s1;
  r2[t] = s2;
  __syncthreads();
  for (int off = 128; off > 0; off >>= 1) {
    if (t < off) { r1[t] += r1[t + off]; r2[t] += r2[t + off]; }
    __syncthreads();
  }
  if (t == 0) {
    const double M = 524288.0;
    double mean = r1[0] / M;
    double var = r2[0] / M - mean * mean;
    if (var < 0.0) var = 0.0;
    float sc = gamma[c] * (float)(1.0 / sqrt(var + 1e-5));
    scale[c] = sc;
    shift[c] = beta[c] - (float)mean * sc;
  }
}

// ---------------------------------------------------------------------------
// P2: act1_raw = W1 * relu(bn0(act0)), store bf16, accumulate stats1.
// grid = 1024 blocks x 8 tiles x 64 rows. 256 thr: 4-row x 4-out register tile.
// ---------------------------------------------------------------------------
__global__ __launch_bounds__(256) void p2_kernel(
    const float* __restrict__ xyz, const float* __restrict__ newxyz,
    const float* __restrict__ P0, const int* __restrict__ gidx,
    const float* __restrict__ w0, const float* __restrict__ w1,
    const float* __restrict__ sc0g, const float* __restrict__ sh0g,
    unsigned short* __restrict__ act1, float* __restrict__ partials1) {
  __shared__ float W1s[64][64];  // [c][o]
  __shared__ float Xs[64][64];   // [c][row]
  __shared__ float w0x[64], w0y[64], w0z[64], sc0[64], sh0[64];
  __shared__ float Sred[256][8];
  const int t = threadIdx.x;
  for (int idx = t; idx < 4096; idx += 256) {
    int c = idx >> 6, o = idx & 63;
    W1s[c][o] = w1[o * 64 + c];
  }
  if (t < 64) {
    w0x[t] = w0[t * 67 + 0];
    w0y[t] = w0[t * 67 + 1];
    w0z[t] = w0[t * 67 + 2];
    sc0[t] = sc0g[t];
    sh0[t] = sh0g[t];
  }
  __syncthreads();
  const int i = t >> 4, j = t & 15;
  const int rl = t >> 2, cq = t & 3;
  float ssum[4] = {}, ssq[4] = {};
  for (int tile = 0; tile < 8; ++tile) {
    const int rowbase = (blockIdx.x * 8 + tile) << 6;
    {
      int r = rowbase + rl;
      int b = r >> 15, s = (r >> 5) & 1023;
      int g = gidx[r];
      const float* Pt = xyz + ((size_t)b * 4096 + g) * 3;
      const float* Ct = newxyz + ((size_t)b * 1024 + s) * 3;
      float dx = Pt[0] - Ct[0], dy = Pt[1] - Ct[1], dz = Pt[2] - Ct[2];
      const float* p0r = P0 + ((size_t)b * 4096 + g) * 64 + cq * 16;
      const float4* p4 = (const float4*)p0r;
      float4 a0 = p4[0], a1 = p4[1], a2 = p4[2], a3 = p4[3];
      float pv[16] = {a0.x, a0.y, a0.z, a0.w, a1.x, a1.y, a1.z, a1.w,
                      a2.x, a2.y, a2.z, a2.w, a3.x, a3.y, a3.z, a3.w};
#pragma unroll
      for (int cc = 0; cc < 16; ++cc) {
        int c = cq * 16 + cc;
        float a = fmaf(w0x[c], dx, fmaf(w0y[c], dy, fmaf(w0z[c], dz, pv[cc])));
        Xs[c][rl] = fmaxf(0.f, fmaf(a, sc0[c], sh0[c]));
      }
    }
    __syncthreads();
    float acc[4][4] = {};
#pragma unroll 4
    for (int c = 0; c < 64; ++c) {
      float4 xv = *(const float4*)&Xs[c][4 * i];
      float4 wv = *(const float4*)&W1s[c][4 * j];
      float xr[4] = {xv.x, xv.y, xv.z, xv.w};
      float wr[4] = {wv.x, wv.y, wv.z, wv.w};
#pragma unroll
      for (int rr = 0; rr < 4; ++rr)
#pragma unroll
        for (int oi = 0; oi < 4; ++oi) acc[rr][oi] = fmaf(xr[rr], wr[oi], acc[rr][oi]);
    }
#pragma unroll
    for (int rr = 0; rr < 4; ++rr) {
      size_t r = (size_t)rowbase + 4 * i + rr;
      ushort4 pk;
      float y0 = acc[rr][0], y1 = acc[rr][1], y2 = acc[rr][2], y3 = acc[rr][3];
      ssum[0] += y0; ssq[0] = fmaf(y0, y0, ssq[0]);
      ssum[1] += y1; ssq[1] = fmaf(y1, y1, ssq[1]);
      ssum[2] += y2; ssq[2] = fmaf(y2, y2, ssq[2]);
      ssum[3] += y3; ssq[3] = fmaf(y3, y3, ssq[3]);
      pk.x = f2bf(y0); pk.y = f2bf(y1); pk.z = f2bf(y2); pk.w = f2bf(y3);
      *(ushort4*)(act1 + r * 64 + 4 * j) = pk;
    }
    __syncthreads();
  }
#pragma unroll
  for (int oi = 0; oi < 4; ++oi) { Sred[t][oi] = ssum[oi]; Sred[t][4 + oi] = ssq[oi]; }
  __syncthreads();
  if (t < 64) {
    int jj = t >> 2, oi = t & 3;
    float s1 = 0.f, s2 = 0.f;
#pragma unroll
    for (int ii = 0; ii < 16; ++ii) {
      s1 += Sred[ii * 16 + jj][oi];
      s2 += Sred[ii * 16 + jj][4 + oi];
    }
    partials1[(size_t)t * 1024 + blockIdx.x] = s1;
    partials1[(size_t)(64 + t) * 1024 + blockIdx.x] = s2;
  }
}

// ---------------------------------------------------------------------------
// P3: stats of act2_raw = W2 * relu(bn1(act1)) (no store; P4 recomputes).
// ---------------------------------------------------------------------------
__global__ __launch_bounds__(256) void p3_kernel(
    const unsigned short* __restrict__ act1, const float* __restrict__ w2,
    const float* __restrict__ sc1g, const float* __restrict__ sh1g,
    float* __restrict__ partials2) {
  __shared__ float W2s[64][128];  // [c][o]
  __shared__ union US { float Xs[64][64]; float Sred[256][16]; } u;
  __shared__ float sc1[64], sh1[64];
  const int t = threadIdx.x;
  for (int idx = t; idx < 8192; idx += 256) {
    int c = idx >> 7, o = idx & 127;
    W2s[c][o] = w2[o * 64 + c];
  }
  if (t < 64) { sc1[t] = sc1g[t]; sh1[t] = sh1g[t]; }
  __syncthreads();
  const int i = t >> 4, j = t & 15;
  const int rl = t >> 2, cq = t & 3;
  float ssum[8] = {}, ssq[8] = {};
  for (int tile = 0; tile < 8; ++tile) {
    const int rowbase = (blockIdx.x * 8 + tile) << 6;
    {
      size_t r = (size_t)rowbase + rl;
      const uint4* pr = (const uint4*)(act1 + r * 64 + cq * 16);
      uint4 aa = pr[0], bb = pr[1];
      unsigned int uu[8] = {aa.x, aa.y, aa.z, aa.w, bb.x, bb.y, bb.z, bb.w};
#pragma unroll
      for (int q = 0; q < 8; ++q) {
        int c = cq * 16 + 2 * q;
        float v0 = bf2f((unsigned short)(uu[q] & 0xffffu));
        float v1 = bf2f((unsigned short)(uu[q] >> 16));
        u.Xs[c][rl] = fmaxf(0.f, fmaf(v0, sc1[c], sh1[c]));
        u.Xs[c + 1][rl] = fmaxf(0.f, fmaf(v1, sc1[c + 1], sh1[c + 1]));
      }
    }
    __syncthreads();
    float acc[4][8] = {};
#pragma unroll 2
    for (int c = 0; c < 64; ++c) {
      float4 xv = *(const float4*)&u.Xs[c][4 * i];
      float4 wa = *(const float4*)&W2s[c][4 * j];
      float4 wb = *(const float4*)&W2s[c][64 + 4 * j];
      float xr[4] = {xv.x, xv.y, xv.z, xv.w};
      float wr[8] = {wa.x, wa.y, wa.z, wa.w, wb.x, wb.y, wb.z, wb.w};
#pragma unroll
      for (int rr = 0; rr < 4; ++rr)
#pragma unroll
        for (int q = 0; q < 8; ++q) acc[rr][q] = fmaf(xr[rr], wr[q], acc[rr][q]);
    }
#pragma unroll
    for (int rr = 0; rr < 4; ++rr)
#pragma unroll
      for (int q = 0; q < 8; ++q) {
        float y = acc[rr][q];
        ssum[q] += y;
        ssq[q] = fmaf(y, y, ssq[q]);
      }
    __syncthreads();
  }
#pragma unroll
  for (int q = 0; q < 8; ++q) { u.Sred[t][q] = ssum[q]; u.Sred[t][8 + q] = ssq[q]; }
  __syncthreads();
  if (t < 128) {
    int o = t;
    int jj = (o & 63) >> 2, oh = o >> 6, oi = o & 3, slot = oh * 4 + oi;
    float s1 = 0.f, s2 = 0.f;
#pragma unroll
    for (int ii = 0; ii < 16; ++ii) {
      s1 += u.Sred[ii * 16 + jj][slot];
      s2 += u.Sred[ii * 16 + jj][8 + slot];
    }
    partials2[(size_t)o * 1024 + blockIdx.x] = s1;
    partials2[(size_t)(128 + o) * 1024 + blockIdx.x] = s2;
  }
}

// ---------------------------------------------------------------------------
// P4: recompute act2, bn2+relu, max over K=32, write feats[b][o][s].
// grid = 8192 blocks, 1 tile = 64 rows = 2 groups each.
// ---------------------------------------------------------------------------
__global__ __launch_bounds__(256) void p4_kernel(
    const unsigned short* __restrict__ act1, const float* __restrict__ w2,
    const float* __restrict__ sc1g, const float* __restrict__ sh1g,
    const float* __restrict__ sc2g, const float* __restrict__ sh2g,
    float* __restrict__ feats) {
  __shared__ float W2s[64][128];
  __shared__ float Xs[64][64];
  __shared__ float Mred[16][132];  // padded stride vs 128 to dodge bank conflicts
  __shared__ float sc1[64], sh1[64], sc2[128], sh2[128];
  const int t = threadIdx.x;
  for (int idx = t; idx < 8192; idx += 256) {
    int c = idx >> 7, o = idx & 127;
    W2s[c][o] = w2[o * 64 + c];
  }
  if (t < 64) { sc1[t] = sc1g[t]; sh1[t] = sh1g[t]; }
  if (t < 128) { sc2[t] = sc2g[t]; sh2[t] = sh2g[t]; }
  __syncthreads();
  const int i = t >> 4, j = t & 15;
  const int rl = t >> 2, cq = t & 3;
  const int rowbase = blockIdx.x << 6;
  {
    size_t r = (size_t)rowbase + rl;
    const uint4* pr = (const uint4*)(act1 + r * 64 + cq * 16);
    uint4 aa = pr[0], bb = pr[1];
    unsigned int uu[8] = {aa.x, aa.y, aa.z, aa.w, bb.x, bb.y, bb.z, bb.w};
#pragma unroll
    for (int q = 0; q < 8; ++q) {
      int c = cq * 16 + 2 * q;
      float v0 = bf2f((unsigned short)(uu[q] & 0xffffu));
      float v1 = bf2f((unsigned short)(uu[q] >> 16));
      Xs[c][rl] = fmaxf(0.f, fmaf(v0, sc1[c], sh1[c]));
      Xs[c + 1][rl] = fmaxf(0.f, fmaf(v1, sc1[c + 1], sh1[c + 1]));
    }
  }
  __syncthreads();
  float acc[4][8] = {};
#pragma unroll 2
  for (int c = 0; c < 64; ++c) {
    float4 xv = *(const float4*)&Xs[c][4 * i];
    float4 wa = *(const float4*)&W2s[c][4 * j];
    float4 wb = *(const float4*)&W2s[c][64 + 4 * j];
    float xr[4] = {xv.x, xv.y, xv.z, xv.w};
    float wr[8] = {wa.x, wa.y, wa.z, wa.w, wb.x, wb.y, wb.z, wb.w};
#pragma unroll
    for (int rr = 0; rr < 4; ++rr)
#pragma unroll
      for (int q = 0; q < 8; ++q) acc[rr][q] = fmaf(xr[rr], wr[q], acc[rr][q]);
  }
  // rows 4i..4i+3 are all in group (i>>3); per-thread max over them.
#pragma unroll
  for (int q = 0; q < 8; ++q) {
    int oh = q >> 2, oi = q & 3;
    int o = 4 * j + 64 * oh + oi;
    float m = 0.f;  // relu output >= 0
#pragma unroll
    for (int rr = 0; rr < 4; ++rr) {
      float v = fmaxf(0.f, fmaf(acc[rr][q], sc2[o], sh2[o]));
      m = fmaxf(m, v);
    }
    Mred[i][o] = m;
  }
  __syncthreads();
  {
    int o = t & 127, g = t >> 7;
    float v = 0.f;
#pragma unroll
    for (int ii = 0; ii < 8; ++ii) v = fmaxf(v, Mred[g * 8 + ii][o]);
    int b = rowbase >> 15;
    int s = ((rowbase >> 5) & 1023) + g;
    feats[(size_t)b * 131072 + (size_t)o * 1024 + s] = v;
  }
}

// ---------------------------------------------------------------------------
extern "C" void kernel_launch(void* const* d_in, const int* in_sizes, int n_in,
                              void* d_out, int out_size, void* d_ws, size_t ws_size,
                              hipStream_t stream) {
  const float* xyz = (const float*)d_in[0];
  const float* points = (const float*)d_in[1];
  const float* w0 = (const float*)d_in[2];
  const float* g0 = (const float*)d_in[3];
  const float* b0 = (const float*)d_in[4];
  const float* w1 = (const float*)d_in[5];
  const float* g1 = (const float*)d_in[6];
  const float* b1 = (const float*)d_in[7];
  const float* w2 = (const float*)d_in[8];
  const float* g2 = (const float*)d_in[9];
  const float* b2 = (const float*)d_in[10];

  float* out = (float*)d_out;
  float* newxyz = out;            // (16,1024,3)
  float* feats = out + 49152;     // (16,128,1024)

  char* ws = (char*)d_ws;
  float* P0 = (float*)ws;                                        // 16 MB  [b][n][64]
  int* gidx = (int*)(ws + (size_t)(16u << 20));                  // 2 MB
  unsigned short* act1 = (unsigned short*)(ws + (size_t)(18u << 20));  // 64 MB bf16
  float* partials0 = (float*)(ws + (size_t)(82u << 20));         // 2 MB   [128][4096]
  float* partials1 = (float*)(ws + (size_t)(84u << 20));         // 0.5 MB [128][1024]
  float* partials2 = (float*)(ws + (size_t)(85u << 20));         // 1 MB   [256][1024]
  float* sc0 = (float*)(ws + (size_t)(86u << 20));               // 6*128 floats
  float* sh0 = sc0 + 128;
  float* sc1 = sc0 + 256;
  float* sh1 = sc0 + 384;
  float* sc2 = sc0 + 512;
  float* sh2 = sc0 + 640;

  fps_kernel<<<16, 256, 0, stream>>>(xyz, newxyz);
  p0_kernel<<<1024, 256, 0, stream>>>(points, w0, P0);
  ballquery_stats0_kernel<<<4096, 256, 0, stream>>>(xyz, newxyz, P0, w0, gidx, partials0);
  finalize_kernel<<<64, 256, 0, stream>>>(partials0, 64, 4096, g0, b0, sc0, sh0);
  p2_kernel<<<1024, 256, 0, stream>>>(xyz, newxyz, P0, gidx, w0, w1, sc0, sh0, act1, partials1);
  finalize_kernel<<<64, 256, 0, stream>>>(partials1, 64, 1024, g1, b1, sc1, sh1);
  p3_kernel<<<1024, 256, 0, stream>>>(act1, w2, sc1, sh1, partials2);
  finalize_kernel<<<128, 256, 0, stream>>>(partials2, 128, 1024, g2, b2, sc2, sh2);
  p4_kernel<<<8192, 256, 0, stream>>>(act1, w2, sc1, sh1, sc2, sh2, feats);
}

// Round 4
// 1330.363 us; speedup vs baseline: 1.4390x; 1.4390x over previous
//
#include <hip/hip_runtime.h>

#define DI static __device__ __forceinline__

DI unsigned short f2bf(float f) {
  unsigned int u = __float_as_uint(f);
  u = (u + 0x7fffu + ((u >> 16) & 1u)) >> 16;
  return (unsigned short)u;
}
DI float bf2f(unsigned short h) { return __uint_as_float(((unsigned int)h) << 16); }

// ---------------------------------------------------------------------------
// FPS: one block per batch, 256 threads, 16 points/thread in registers.
// Distance arithmetic is the exact rn sequence that passed bit-exact in r3:
//   d = ((dx*dx + dy*dy) + dz*dz), no FMA. DO NOT TOUCH.
// Argmax re-engineered for latency (semantics identical: strict >, first
// index wins ties):
//   - pack (dist_bits<<32)|~idx into u64, single lexicographic max
//     (dist >= 0 so float bits order as uint; bigger ~idx = smaller idx)
//   - __shfl_xor butterfly (6 levels) per wave
//   - xyz mirrored in LDS: every thread unpacks winner index and
//     broadcast-reads the centroid -> no election, no 2nd barrier
//   - parity-double-buffered per-wave slots -> exactly 1 barrier/step
// ---------------------------------------------------------------------------
__global__ __launch_bounds__(256) void fps_kernel(const float* __restrict__ xyz,
                                                  float* __restrict__ newxyz) {
  const int b = blockIdx.x;
  const int t = threadIdx.x;
  const int lane = t & 63, wid = t >> 6;
  const float* X = xyz + (size_t)b * 4096 * 3;
  __shared__ float XL[4096 * 3];
  __shared__ unsigned long long slot[2][4];
  for (int idx = t; idx < 12288; idx += 256) XL[idx] = X[idx];
  float px[16], py[16], pz[16], dist[16];
#pragma unroll
  for (int j = 0; j < 16; ++j) {
    int i = t + (j << 8);
    px[j] = X[i * 3 + 0];
    py[j] = X[i * 3 + 1];
    pz[j] = X[i * 3 + 2];
    dist[j] = 3.402823466e38f;
  }
  __syncthreads();
  float cx = XL[0], cy = XL[1], cz = XL[2];  // farthest = 0 initially
  const unsigned int nt = ~(unsigned int)t;
  float* out = newxyz + (size_t)b * 1024 * 3;
  for (int s = 0; s < 1024; ++s) {
    if (t == 0) { out[s * 3 + 0] = cx; out[s * 3 + 1] = cy; out[s * 3 + 2] = cz; }
    float bv = -1.0f;           // j=0 always wins (nd >= 0 > -1)
    unsigned int bl = 0;
#pragma unroll
    for (int j = 0; j < 16; ++j) {
      float dx = __fsub_rn(px[j], cx);
      float dy = __fsub_rn(py[j], cy);
      float dz = __fsub_rn(pz[j], cz);
      float d = __fadd_rn(__fadd_rn(__fmul_rn(dx, dx), __fmul_rn(dy, dy)), __fmul_rn(dz, dz));
      float nd = fminf(dist[j], d);
      dist[j] = nd;
      bool better = (nd > bv);  // strict >: earlier (smaller) index kept on ties
      bv = better ? nd : bv;
      bl = better ? (nt - (unsigned int)(j << 8)) : bl;  // = ~(t + j*256)
    }
    unsigned long long best =
        ((unsigned long long)__float_as_uint(bv) << 32) | (unsigned long long)bl;
#pragma unroll
    for (int m = 1; m < 64; m <<= 1) {
      unsigned long long o = __shfl_xor(best, m, 64);
      best = (o > best) ? o : best;
    }
    if (lane == 0) slot[s & 1][wid] = best;
    __syncthreads();
    unsigned long long w0v = slot[s & 1][0], w1v = slot[s & 1][1];
    unsigned long long w2v = slot[s & 1][2], w3v = slot[s & 1][3];
    unsigned long long m01 = (w0v > w1v) ? w0v : w1v;
    unsigned long long m23 = (w2v > w3v) ? w2v : w3v;
    unsigned long long win = (m01 > m23) ? m01 : m23;
    int fi = (int)(~(unsigned int)win);  // unpack index, in [0,4095]
    cx = XL[fi * 3 + 0];
    cy = XL[fi * 3 + 1];
    cz = XL[fi * 3 + 2];
  }
}

// ---------------------------------------------------------------------------
// P0[b][n][o] = sum_c W0[o][3+c] * points[b][c][n]   (pushes mm0 through gather)
// block = 64 n x 64 o, 256 threads, register 4x4 tiles. grid = 16*64 = 1024.
// ---------------------------------------------------------------------------
__global__ __launch_bounds__(256) void p0_kernel(const float* __restrict__ points,
                                                 const float* __restrict__ w0,
                                                 float* __restrict__ P0) {
  const int b = blockIdx.x >> 6;
  const int n0 = (blockIdx.x & 63) << 6;
  const int t = threadIdx.x;
  __shared__ float W[64][64];  // [c][o]
  for (int idx = t; idx < 4096; idx += 256) {
    int c = idx >> 6, o = idx & 63;
    W[c][o] = w0[o * 67 + 3 + c];
  }
  __syncthreads();
  const int i = t >> 4, j = t & 15;
  const float* Pb = points + (size_t)b * 64 * 4096 + n0 + 4 * i;
  float acc[4][4] = {};
  for (int c = 0; c < 64; ++c) {
    float4 xv = *(const float4*)(Pb + (size_t)c * 4096);
    float4 wv = *(const float4*)&W[c][4 * j];
    float xr[4] = {xv.x, xv.y, xv.z, xv.w};
    float wr[4] = {wv.x, wv.y, wv.z, wv.w};
#pragma unroll
    for (int rr = 0; rr < 4; ++rr)
#pragma unroll
      for (int oi = 0; oi < 4; ++oi) acc[rr][oi] = fmaf(xr[rr], wr[oi], acc[rr][oi]);
  }
#pragma unroll
  for (int rr = 0; rr < 4; ++rr) {
    float4 vv = make_float4(acc[rr][0], acc[rr][1], acc[rr][2], acc[rr][3]);
    *(float4*)(P0 + ((size_t)b * 4096 + n0 + 4 * i + rr) * 64 + 4 * j) = vv;
  }
}

// ---------------------------------------------------------------------------
// Ball query fused with layer-0 stats accumulation.
// sqr emulates XLA-CPU fp32 arithmetic of the reference (VERIFIED r3):
//   dot  = fma chain over d; cs/xs = plain rn; sqr = rn((cs+xs) - 2*dot)
// One wave per group, 4 groups per block, grid = 4096.
// ---------------------------------------------------------------------------
__global__ __launch_bounds__(256) void ballquery_stats0_kernel(
    const float* __restrict__ xyz, const float* __restrict__ newxyz,
    const float* __restrict__ P0, const float* __restrict__ w0,
    int* __restrict__ gidx, float* __restrict__ partials0) {
  const int t = threadIdx.x;
  const int lane = t & 63, w = t >> 6;
  const int gid = blockIdx.x * 4 + w;  // 0..16383
  const int b = gid >> 10;
  __shared__ int sel[4][32];
  __shared__ float red[4][128];
  const float* Xb = xyz + (size_t)b * 4096 * 3;
  const float cx = newxyz[(size_t)gid * 3 + 0];
  const float cy = newxyz[(size_t)gid * 3 + 1];
  const float cz = newxyz[(size_t)gid * 3 + 2];
  const float cs = __fadd_rn(__fadd_rn(__fmul_rn(cx, cx), __fmul_rn(cy, cy)), __fmul_rn(cz, cz));
  int cnt = 0, first = 0;
  bool found = false;
  for (int base = 0; base < 4096; base += 64) {
    int i = base + lane;
    float x = Xb[i * 3 + 0], y = Xb[i * 3 + 1], z = Xb[i * 3 + 2];
    float xs = __fadd_rn(__fadd_rn(__fmul_rn(x, x), __fmul_rn(y, y)), __fmul_rn(z, z));
    float dot = fmaf(cz, z, fmaf(cy, y, __fmul_rn(cx, x)));  // fma chain, d=0,1,2
    float sqr = __fsub_rn(__fadd_rn(cs, xs), __fmul_rn(2.0f, dot));
    bool ok = sqr <= 0.04f;
    unsigned long long mask = __ballot(ok);
    if (!found && mask != 0ull) { first = base + __builtin_ctzll(mask); found = true; }
    int pre = __popcll(mask & ((1ull << lane) - 1ull));
    int pos = cnt + pre;
    if (ok && pos < 32) sel[w][pos] = i;
    cnt += (int)__popcll(mask);
    if (cnt >= 32) break;
  }
  if (cnt < 32) {
    int pad = found ? first : 0;
    for (int p = cnt + lane; p < 32; p += 64) sel[w][p] = pad;
  }
  __syncthreads();
  if (lane < 32) gidx[(size_t)gid * 32 + lane] = sel[w][lane];
  // ---- stats for act0 (pre-BN layer0 output): lane = channel c ----
  const int c = lane;
  float wx = w0[c * 67 + 0], wy = w0[c * 67 + 1], wz = w0[c * 67 + 2];
  float ssum = 0.f, ssq = 0.f;
  const float* P0b = P0 + (size_t)b * 4096 * 64;
  for (int k = 0; k < 32; ++k) {
    int g = sel[w][k];
    float gx = Xb[g * 3 + 0] - cx, gy = Xb[g * 3 + 1] - cy, gz = Xb[g * 3 + 2] - cz;
    float a0 = fmaf(wx, gx, fmaf(wy, gy, fmaf(wz, gz, P0b[(size_t)g * 64 + c])));
    ssum += a0;
    ssq = fmaf(a0, a0, ssq);
  }
  red[w][c] = ssum;
  red[w][c + 64] = ssq;
  __syncthreads();
  if (t < 128) {
    float acc = red[0][t] + red[1][t] + red[2][t] + red[3][t];
    partials0[(size_t)t * 4096 + blockIdx.x] = acc;
  }
}

// ---------------------------------------------------------------------------
// finalize BN stats: scale = g*rsqrt(var+eps), shift = b - mean*scale
// ---------------------------------------------------------------------------
__global__ __launch_bounds__(256) void finalize_kernel(
    const float* __restrict__ partials, int C, int nblk,
    const float* __restrict__ gamma, const float* __restrict__ beta,
    float* __restrict__ scale, float* __restrict__ shift) {
  const int c = blockIdx.x, t = threadIdx.x;
  double s1 = 0.0, s2 = 0.0;
  for (int k = t; k < nblk; k += 256) {
    s1 += (double)partials[(size_t)c * nblk + k];
    s2 += (double)partials[(size_t)(C + c) * nblk + k];
  }
  __shared__ double r1[256], r2[256];
  r1[t] = s1;
  r2[t] = s2;
  __syncthreads();
  for (int off = 128; off > 0; off >>= 1) {
    if (t < off) { r1[t] += r1[t + off]; r2[t] += r2[t + off]; }
    __syncthreads();
  }
  if (t == 0) {
    const double M = 524288.0;
    double mean = r1[0] / M;
    double var = r2[0] / M - mean * mean;
    if (var < 0.0) var = 0.0;
    float sc = gamma[c] * (float)(1.0 / sqrt(var + 1e-5));
    scale[c] = sc;
    shift[c] = beta[c] - (float)mean * sc;
  }
}

// ---------------------------------------------------------------------------
// P2: act1_raw = W1 * relu(bn0(act0)), store bf16, accumulate stats1.
// grid = 1024 blocks x 8 tiles x 64 rows. 256 thr: 4-row x 4-out register tile.
// ---------------------------------------------------------------------------
__global__ __launch_bounds__(256) void p2_kernel(
    const float* __restrict__ xyz, const float* __restrict__ newxyz,
    const float* __restrict__ P0, const int* __restrict__ gidx,
    const float* __restrict__ w0, const float* __restrict__ w1,
    const float* __restrict__ sc0g, const float* __restrict__ sh0g,
    unsigned short* __restrict__ act1, float* __restrict__ partials1) {
  __shared__ float W1s[64][64];  // [c][o]
  __shared__ float Xs[64][64];   // [c][row]
  __shared__ float w0x[64], w0y[64], w0z[64], sc0[64], sh0[64];
  __shared__ float Sred[256][8];
  const int t = threadIdx.x;
  for (int idx = t; idx < 4096; idx += 256) {
    int c = idx >> 6, o = idx & 63;
    W1s[c][o] = w1[o * 64 + c];
  }
  if (t < 64) {
    w0x[t] = w0[t * 67 + 0];
    w0y[t] = w0[t * 67 + 1];
    w0z[t] = w0[t * 67 + 2];
    sc0[t] = sc0g[t];
    sh0[t] = sh0g[t];
  }
  __syncthreads();
  const int i = t >> 4, j = t & 15;
  const int rl = t >> 2, cq = t & 3;
  float ssum[4] = {}, ssq[4] = {};
  for (int tile = 0; tile < 8; ++tile) {
    const int rowbase = (blockIdx.x * 8 + tile) << 6;
    {
      int r = rowbase + rl;
      int b = r >> 15, s = (r >> 5) & 1023;
      int g = gidx[r];
      const float* Pt = xyz + ((size_t)b * 4096 + g) * 3;
      const float* Ct = newxyz + ((size_t)b * 1024 + s) * 3;
      float dx = Pt[0] - Ct[0], dy = Pt[1] - Ct[1], dz = Pt[2] - Ct[2];
      const float* p0r = P0 + ((size_t)b * 4096 + g) * 64 + cq * 16;
      const float4* p4 = (const float4*)p0r;
      float4 a0 = p4[0], a1 = p4[1], a2 = p4[2], a3 = p4[3];
      float pv[16] = {a0.x, a0.y, a0.z, a0.w, a1.x, a1.y, a1.z, a1.w,
                      a2.x, a2.y, a2.z, a2.w, a3.x, a3.y, a3.z, a3.w};
#pragma unroll
      for (int cc = 0; cc < 16; ++cc) {
        int c = cq * 16 + cc;
        float a = fmaf(w0x[c], dx, fmaf(w0y[c], dy, fmaf(w0z[c], dz, pv[cc])));
        Xs[c][rl] = fmaxf(0.f, fmaf(a, sc0[c], sh0[c]));
      }
    }
    __syncthreads();
    float acc[4][4] = {};
#pragma unroll 4
    for (int c = 0; c < 64; ++c) {
      float4 xv = *(const float4*)&Xs[c][4 * i];
      float4 wv = *(const float4*)&W1s[c][4 * j];
      float xr[4] = {xv.x, xv.y, xv.z, xv.w};
      float wr[4] = {wv.x, wv.y, wv.z, wv.w};
#pragma unroll
      for (int rr = 0; rr < 4; ++rr)
#pragma unroll
        for (int oi = 0; oi < 4; ++oi) acc[rr][oi] = fmaf(xr[rr], wr[oi], acc[rr][oi]);
    }
#pragma unroll
    for (int rr = 0; rr < 4; ++rr) {
      size_t r = (size_t)rowbase + 4 * i + rr;
      ushort4 pk;
      float y0 = acc[rr][0], y1 = acc[rr][1], y2 = acc[rr][2], y3 = acc[rr][3];
      ssum[0] += y0; ssq[0] = fmaf(y0, y0, ssq[0]);
      ssum[1] += y1; ssq[1] = fmaf(y1, y1, ssq[1]);
      ssum[2] += y2; ssq[2] = fmaf(y2, y2, ssq[2]);
      ssum[3] += y3; ssq[3] = fmaf(y3, y3, ssq[3]);
      pk.x = f2bf(y0); pk.y = f2bf(y1); pk.z = f2bf(y2); pk.w = f2bf(y3);
      *(ushort4*)(act1 + r * 64 + 4 * j) = pk;
    }
    __syncthreads();
  }
#pragma unroll
  for (int oi = 0; oi < 4; ++oi) { Sred[t][oi] = ssum[oi]; Sred[t][4 + oi] = ssq[oi]; }
  __syncthreads();
  if (t < 64) {
    int jj = t >> 2, oi = t & 3;
    float s1 = 0.f, s2 = 0.f;
#pragma unroll
    for (int ii = 0; ii < 16; ++ii) {
      s1 += Sred[ii * 16 + jj][oi];
      s2 += Sred[ii * 16 + jj][4 + oi];
    }
    partials1[(size_t)t * 1024 + blockIdx.x] = s1;
    partials1[(size_t)(64 + t) * 1024 + blockIdx.x] = s2;
  }
}

// ---------------------------------------------------------------------------
// P3: stats of act2_raw = W2 * relu(bn1(act1)) (no store; P4 recomputes).
// ---------------------------------------------------------------------------
__global__ __launch_bounds__(256) void p3_kernel(
    const unsigned short* __restrict__ act1, const float* __restrict__ w2,
    const float* __restrict__ sc1g, const float* __restrict__ sh1g,
    float* __restrict__ partials2) {
  __shared__ float W2s[64][128];  // [c][o]
  __shared__ union US { float Xs[64][64]; float Sred[256][16]; } u;
  __shared__ float sc1[64], sh1[64];
  const int t = threadIdx.x;
  for (int idx = t; idx < 8192; idx += 256) {
    int c = idx >> 7, o = idx & 127;
    W2s[c][o] = w2[o * 64 + c];
  }
  if (t < 64) { sc1[t] = sc1g[t]; sh1[t] = sh1g[t]; }
  __syncthreads();
  const int i = t >> 4, j = t & 15;
  const int rl = t >> 2, cq = t & 3;
  float ssum[8] = {}, ssq[8] = {};
  for (int tile = 0; tile < 8; ++tile) {
    const int rowbase = (blockIdx.x * 8 + tile) << 6;
    {
      size_t r = (size_t)rowbase + rl;
      const uint4* pr = (const uint4*)(act1 + r * 64 + cq * 16);
      uint4 aa = pr[0], bb = pr[1];
      unsigned int uu[8] = {aa.x, aa.y, aa.z, aa.w, bb.x, bb.y, bb.z, bb.w};
#pragma unroll
      for (int q = 0; q < 8; ++q) {
        int c = cq * 16 + 2 * q;
        float v0 = bf2f((unsigned short)(uu[q] & 0xffffu));
        float v1 = bf2f((unsigned short)(uu[q] >> 16));
        u.Xs[c][rl] = fmaxf(0.f, fmaf(v0, sc1[c], sh1[c]));
        u.Xs[c + 1][rl] = fmaxf(0.f, fmaf(v1, sc1[c + 1], sh1[c + 1]));
      }
    }
    __syncthreads();
    float acc[4][8] = {};
#pragma unroll 2
    for (int c = 0; c < 64; ++c) {
      float4 xv = *(const float4*)&u.Xs[c][4 * i];
      float4 wa = *(const float4*)&W2s[c][4 * j];
      float4 wb = *(const float4*)&W2s[c][64 + 4 * j];
      float xr[4] = {xv.x, xv.y, xv.z, xv.w};
      float wr[8] = {wa.x, wa.y, wa.z, wa.w, wb.x, wb.y, wb.z, wb.w};
#pragma unroll
      for (int rr = 0; rr < 4; ++rr)
#pragma unroll
        for (int q = 0; q < 8; ++q) acc[rr][q] = fmaf(xr[rr], wr[q], acc[rr][q]);
    }
#pragma unroll
    for (int rr = 0; rr < 4; ++rr)
#pragma unroll
      for (int q = 0; q < 8; ++q) {
        float y = acc[rr][q];
        ssum[q] += y;
        ssq[q] = fmaf(y, y, ssq[q]);
      }
    __syncthreads();
  }
#pragma unroll
  for (int q = 0; q < 8; ++q) { u.Sred[t][q] = ssum[q]; u.Sred[t][8 + q] = ssq[q]; }
  __syncthreads();
  if (t < 128) {
    int o = t;
    int jj = (o & 63) >> 2, oh = o >> 6, oi = o & 3, slot = oh * 4 + oi;
    float s1 = 0.f, s2 = 0.f;
#pragma unroll
    for (int ii = 0; ii < 16; ++ii) {
      s1 += u.Sred[ii * 16 + jj][slot];
      s2 += u.Sred[ii * 16 + jj][8 + slot];
    }
    partials2[(size_t)o * 1024 + blockIdx.x] = s1;
    partials2[(size_t)(128 + o) * 1024 + blockIdx.x] = s2;
  }
}

// ---------------------------------------------------------------------------
// P4: recompute act2, bn2+relu, max over K=32, write feats[b][o][s].
// grid = 8192 blocks, 1 tile = 64 rows = 2 groups each.
// ---------------------------------------------------------------------------
__global__ __launch_bounds__(256) void p4_kernel(
    const unsigned short* __restrict__ act1, const float* __restrict__ w2,
    const float* __restrict__ sc1g, const float* __restrict__ sh1g,
    const float* __restrict__ sc2g, const float* __restrict__ sh2g,
    float* __restrict__ feats) {
  __shared__ float W2s[64][128];
  __shared__ float Xs[64][64];
  __shared__ float Mred[16][132];  // padded stride vs 128 to dodge bank conflicts
  __shared__ float sc1[64], sh1[64], sc2[128], sh2[128];
  const int t = threadIdx.x;
  for (int idx = t; idx < 8192; idx += 256) {
    int c = idx >> 7, o = idx & 127;
    W2s[c][o] = w2[o * 64 + c];
  }
  if (t < 64) { sc1[t] = sc1g[t]; sh1[t] = sh1g[t]; }
  if (t < 128) { sc2[t] = sc2g[t]; sh2[t] = sh2g[t]; }
  __syncthreads();
  const int i = t >> 4, j = t & 15;
  const int rl = t >> 2, cq = t & 3;
  const int rowbase = blockIdx.x << 6;
  {
    size_t r = (size_t)rowbase + rl;
    const uint4* pr = (const uint4*)(act1 + r * 64 + cq * 16);
    uint4 aa = pr[0], bb = pr[1];
    unsigned int uu[8] = {aa.x, aa.y, aa.z, aa.w, bb.x, bb.y, bb.z, bb.w};
#pragma unroll
    for (int q = 0; q < 8; ++q) {
      int c = cq * 16 + 2 * q;
      float v0 = bf2f((unsigned short)(uu[q] & 0xffffu));
      float v1 = bf2f((unsigned short)(uu[q] >> 16));
      Xs[c][rl] = fmaxf(0.f, fmaf(v0, sc1[c], sh1[c]));
      Xs[c + 1][rl] = fmaxf(0.f, fmaf(v1, sc1[c + 1], sh1[c + 1]));
    }
  }
  __syncthreads();
  float acc[4][8] = {};
#pragma unroll 2
  for (int c = 0; c < 64; ++c) {
    float4 xv = *(const float4*)&Xs[c][4 * i];
    float4 wa = *(const float4*)&W2s[c][4 * j];
    float4 wb = *(const float4*)&W2s[c][64 + 4 * j];
    float xr[4] = {xv.x, xv.y, xv.z, xv.w};
    float wr[8] = {wa.x, wa.y, wa.z, wa.w, wb.x, wb.y, wb.z, wb.w};
#pragma unroll
    for (int rr = 0; rr < 4; ++rr)
#pragma unroll
      for (int q = 0; q < 8; ++q) acc[rr][q] = fmaf(xr[rr], wr[q], acc[rr][q]);
  }
  // rows 4i..4i+3 are all in group (i>>3); per-thread max over them.
#pragma unroll
  for (int q = 0; q < 8; ++q) {
    int oh = q >> 2, oi = q & 3;
    int o = 4 * j + 64 * oh + oi;
    float m = 0.f;  // relu output >= 0
#pragma unroll
    for (int rr = 0; rr < 4; ++rr) {
      float v = fmaxf(0.f, fmaf(acc[rr][q], sc2[o], sh2[o]));
      m = fmaxf(m, v);
    }
    Mred[i][o] = m;
  }
  __syncthreads();
  {
    int o = t & 127, g = t >> 7;
    float v = 0.f;
#pragma unroll
    for (int ii = 0; ii < 8; ++ii) v = fmaxf(v, Mred[g * 8 + ii][o]);
    int b = rowbase >> 15;
    int s = ((rowbase >> 5) & 1023) + g;
    feats[(size_t)b * 131072 + (size_t)o * 1024 + s] = v;
  }
}

// ---------------------------------------------------------------------------
extern "C" void kernel_launch(void* const* d_in, const int* in_sizes, int n_in,
                              void* d_out, int out_size, void* d_ws, size_t ws_size,
                              hipStream_t stream) {
  const float* xyz = (const float*)d_in[0];
  const float* points = (const float*)d_in[1];
  const float* w0 = (const float*)d_in[2];
  const float* g0 = (const float*)d_in[3];
  const float* b0 = (const float*)d_in[4];
  const float* w1 = (const float*)d_in[5];
  const float* g1 = (const float*)d_in[6];
  const float* b1 = (const float*)d_in[7];
  const float* w2 = (const float*)d_in[8];
  const float* g2 = (const float*)d_in[9];
  const float* b2 = (const float*)d_in[10];

  float* out = (float*)d_out;
  float* newxyz = out;            // (16,1024,3)
  float* feats = out + 49152;     // (16,128,1024)

  char* ws = (char*)d_ws;
  float* P0 = (float*)ws;                                        // 16 MB  [b][n][64]
  int* gidx = (int*)(ws + (size_t)(16u << 20));                  // 2 MB
  unsigned short* act1 = (unsigned short*)(ws + (size_t)(18u << 20));  // 64 MB bf16
  float* partials0 = (float*)(ws + (size_t)(82u << 20));         // 2 MB   [128][4096]
  float* partials1 = (float*)(ws + (size_t)(84u << 20));         // 0.5 MB [128][1024]
  float* partials2 = (float*)(ws + (size_t)(85u << 20));         // 1 MB   [256][1024]
  float* sc0 = (float*)(ws + (size_t)(86u << 20));               // 6*128 floats
  float* sh0 = sc0 + 128;
  float* sc1 = sc0 + 256;
  float* sh1 = sc0 + 384;
  float* sc2 = sc0 + 512;
  float* sh2 = sc0 + 640;

  fps_kernel<<<16, 256, 0, stream>>>(xyz, newxyz);
  p0_kernel<<<1024, 256, 0, stream>>>(points, w0, P0);
  ballquery_stats0_kernel<<<4096, 256, 0, stream>>>(xyz, newxyz, P0, w0, gidx, partials0);
  finalize_kernel<<<64, 256, 0, stream>>>(partials0, 64, 4096, g0, b0, sc0, sh0);
  p2_kernel<<<1024, 256, 0, stream>>>(xyz, newxyz, P0, gidx, w0, w1, sc0, sh0, act1, partials1);
  finalize_kernel<<<64, 256, 0, stream>>>(partials1, 64, 1024, g1, b1, sc1, sh1);
  p3_kernel<<<1024, 256, 0, stream>>>(act1, w2, sc1, sh1, partials2);
  finalize_kernel<<<128, 256, 0, stream>>>(partials2, 128, 1024, g2, b2, sc2, sh2);
  p4_kernel<<<8192, 256, 0, stream>>>(act1, w2, sc1, sh1, sc2, sh2, feats);
}